// Round 8
// baseline (6178.796 us; speedup 1.0000x reference)
//
#include <hip/hip_runtime.h>

#define BATCH    128
#define NPTS     32768
#define KOUT     1024
#define NTHREADS 1024
#define PPT      (NPTS / NTHREADS)   // 32 points per thread
#define NBLK     (PPT / 4)           // 8 float4 blocks per thread

// One block per batch, 1024 threads = 16 waves = 4 waves/SIMD.
// Learned rounds 2-7: the register allocator grants at most 128 VGPRs
// (static LDS raised it 64->128; waves_per_eu(2,2) for 256 was ignored).
// So we size the working set to FIT 128: PPT=32 -> 96 coord regs + temps.
// mindist lives in static LDS, owned CONTIGUOUSLY per thread so it moves
// as 8x ds_read_b128/ds_write_b128 instead of 64x b32 (rounds 2-7 spent
// ~5.9k cyc/iter on scalar LDS ops). XOR swizzle (k ^ (tid&7)) spreads the
// 128-B-stride rows over all 32 banks (else 16-way conflict). Writes are
// skipped wave-uniformly when no lane's tile changed.
__global__ __launch_bounds__(NTHREADS)
void fps_kernel(const float* __restrict__ x, float* __restrict__ out) {
    __shared__ float4 s_md4[NPTS / 4];   // 128 KiB, static
    __shared__ float  s_redv[16];
    __shared__ int    s_redi[16];
    __shared__ float  s_pt[3];

    const int b   = blockIdx.x;
    const int tid = threadIdx.x;
    const float* __restrict__ xb = x + (size_t)b * 3 * NPTS;
    float* __restrict__ ob = out + (size_t)b * 3 * KOUT;

    const int tid7  = tid & 7;
    const int sbase = tid * NBLK;        // this thread's 8 float4 slots

    // Load this thread's 32 contiguous points: n = tid*32 + i.
    // Per wave each load covers a contiguous 8 KB window -> L1-friendly.
    float xs[PPT], ys[PPT], zs[PPT];
#pragma unroll
    for (int i = 0; i < PPT; ++i) {
        const int n = tid * PPT + i;
        xs[i] = xb[n];
        ys[i] = xb[NPTS + n];
        zs[i] = xb[2 * NPTS + n];
    }
    // Init mindist (any covering write pattern is fine: all bytes = 1e10).
#pragma unroll
    for (int k = 0; k < NBLK; ++k)
        s_md4[sbase + k] = make_float4(1e10f, 1e10f, 1e10f, 1e10f);

    // First selected point is index 0.
    float px = xb[0], py = xb[NPTS], pz = xb[2 * NPTS];
    if (tid == 0) {
        ob[0] = px; ob[KOUT] = py; ob[2 * KOUT] = pz;
    }
    __syncthreads();

    const int lane = tid & 63;
    const int wave = tid >> 6;

    for (int j = 1; j < KOUT; ++j) {
        float best = -1.0f;
        int   bi   = 0x7fffffff;

        // Distance update + running (first-occurrence) argmax.
        // Bit-exact vs reference (verified rounds 2-7, absmax 0):
        //   d = fma(dz,dz, fma(dy,dy, rn(dx*dx)))
#pragma unroll
        for (int k = 0; k < NBLK; ++k) {
            const int slot = sbase + (k ^ tid7);   // XOR bank swizzle
            const float4 mo = s_md4[slot];
            float m[4];
#pragma unroll
            for (int q = 0; q < 4; ++q) {
                const int i = 4 * k + q;
                const float dx = __fsub_rn(xs[i], px);
                const float dy = __fsub_rn(ys[i], py);
                const float dz = __fsub_rn(zs[i], pz);
                const float d  = __fmaf_rn(dz, dz,
                                  __fmaf_rn(dy, dy,
                                    __fmul_rn(dx, dx)));
                const float o  = (q == 0) ? mo.x : (q == 1) ? mo.y
                               : (q == 2) ? mo.z : mo.w;
                m[q] = fminf(o, d);
                // contiguous indices increase with i: strict > keeps the
                // earliest (lowest-index) occurrence of the max
                if (m[q] > best) { best = m[q]; bi = tid * PPT + i; }
            }
            const bool chg = (m[0] < mo.x) || (m[1] < mo.y) ||
                             (m[2] < mo.z) || (m[3] < mo.w);
            if (__any(chg))   // wave-uniform: skip write when tile unchanged
                s_md4[slot] = make_float4(m[0], m[1], m[2], m[3]);
        }

        // Wave-level butterfly argmax (tie-break: smaller index wins).
#pragma unroll
        for (int s = 1; s < 64; s <<= 1) {
            const float ov = __shfl_xor(best, s, 64);
            const int   oi = __shfl_xor(bi,   s, 64);
            if (ov > best || (ov == best && oi < bi)) { best = ov; bi = oi; }
        }
        if (lane == 0) { s_redv[wave] = best; s_redi[wave] = bi; }
        __syncthreads();

        // Cross-wave reduce (16 partials) in wave 0; lane 0 fetches the
        // winner's coords from global (L1/L2-resident) and publishes.
        if (wave == 0) {
            float v  = (lane < 16) ? s_redv[lane] : -1.0f;
            int   vi = (lane < 16) ? s_redi[lane] : 0x7fffffff;
#pragma unroll
            for (int s = 1; s < 16; s <<= 1) {
                const float ov = __shfl_xor(v,  s, 64);
                const int   oi = __shfl_xor(vi, s, 64);
                if (ov > v || (ov == v && oi < vi)) { v = ov; vi = oi; }
            }
            if (lane == 0) {
                const float sx = xb[vi];
                const float sy = xb[NPTS + vi];
                const float sz = xb[2 * NPTS + vi];
                s_pt[0] = sx; s_pt[1] = sy; s_pt[2] = sz;
                ob[j] = sx; ob[KOUT + j] = sy; ob[2 * KOUT + j] = sz;
            }
        }
        __syncthreads();
        px = s_pt[0]; py = s_pt[1]; pz = s_pt[2];
    }
}

extern "C" void kernel_launch(void* const* d_in, const int* in_sizes, int n_in,
                              void* d_out, int out_size, void* d_ws, size_t ws_size,
                              hipStream_t stream) {
    const float* x = (const float*)d_in[0];
    float* out = (float*)d_out;
    fps_kernel<<<BATCH, NTHREADS, 0, stream>>>(x, out);
}